// Round 1
// baseline (1149.339 us; speedup 1.0000x reference)
//
#include <hip/hip_runtime.h>

#define D 64

// ---------------- degree: deg[dst] += 1 ----------------
__global__ void deg_kernel(const int* __restrict__ dst, float* __restrict__ deg, int E) {
    int i = blockIdx.x * blockDim.x + threadIdx.x;
    int n = gridDim.x * blockDim.x;
    for (int e = i; e < E; e += n) atomicAdd(&deg[dst[e]], 1.0f);
}

// ---------------- aggregate: agg[dst][:] += h[src][:], one wave per edge ----------------
__global__ void aggregate_kernel(const float* __restrict__ h,
                                 const int* __restrict__ src,
                                 const int* __restrict__ dst,
                                 float* __restrict__ agg, int E) {
    int wid  = (blockIdx.x * blockDim.x + threadIdx.x) >> 6;
    int lane = threadIdx.x & 63;
    int nw   = (gridDim.x * blockDim.x) >> 6;
    for (int e = wid; e < E; e += nw) {
        int s = src[e];
        int d = dst[e];
        float v = h[(size_t)s * D + lane];            // coalesced 256B gather
        atomicAdd(&agg[(size_t)d * D + lane], v);     // coalesced atomic scatter
    }
}

// ---------------- transform: out = [relu](agg*inv_deg @ Wl^T + bl + h @ Wr^T) ----------------
// Safe for out == agg (each row fully staged into LDS before being overwritten).
__global__ __launch_bounds__(256) void transform_kernel(
    const float* __restrict__ agg, const float* __restrict__ h,
    const float* __restrict__ Wl, const float* __restrict__ bl,
    const float* __restrict__ Wr, const float* __restrict__ deg,
    float* __restrict__ out, int N, int relu) {
    __shared__ float WlT[D * D];   // transposed: WlT[k*D+o] = Wl[o*D+k]
    __shared__ float WrT[D * D];
    __shared__ float bias[D];
    __shared__ float aggRow[4][D];
    __shared__ float hRow[4][D];

    int t = threadIdx.x;
    for (int i = t; i < D * D; i += 256) {
        int o = i / D, k = i % D;
        WlT[k * D + o] = Wl[i];
        WrT[k * D + o] = Wr[i];
    }
    if (t < D) bias[t] = bl[t];
    __syncthreads();

    int rowBase = blockIdx.x * 64;   // 64 rows per block
    int sub = t >> 6;                // 0..3 (row within group of 4)
    int o   = t & 63;                // output feature

    for (int g = 0; g < 16; ++g) {
        int rr = rowBase + g * 4 + sub;
        __syncthreads();             // protect LDS rows from previous iteration
        if (rr < N) {
            aggRow[sub][o] = agg[(size_t)rr * D + o];
            hRow[sub][o]   = h[(size_t)rr * D + o];
        }
        __syncthreads();
        if (rr < N) {
            float inv = 1.0f / fmaxf(deg[rr], 1.0f);
            float accL = 0.0f, accR = 0.0f;
            #pragma unroll
            for (int k = 0; k < D; ++k) {
                accL += aggRow[sub][k] * WlT[k * D + o];  // aggRow: broadcast (free)
                accR += hRow[sub][k]   * WrT[k * D + o];  // WlT/WrT: 2-way alias (free)
            }
            float acc = bias[o] + inv * accL + accR;
            if (relu) acc = fmaxf(acc, 0.0f);
            out[(size_t)rr * D + o] = acc;
        }
    }
}

// ---------------- classifier: out[r][c] = h[r] . Wout[c] + bout[c], wave per row ----------------
__global__ void classify_kernel(const float* __restrict__ h,
                                const float* __restrict__ Wout,
                                const float* __restrict__ bout,
                                float* __restrict__ out, int N) {
    int wid  = (blockIdx.x * blockDim.x + threadIdx.x) >> 6;
    int lane = threadIdx.x & 63;
    int nw   = (gridDim.x * blockDim.x) >> 6;
    float w0 = Wout[lane];
    float w1 = Wout[D + lane];
    float b0 = bout[0], b1 = bout[1];
    for (int r = wid; r < N; r += nw) {
        float v  = h[(size_t)r * D + lane];
        float a0 = v * w0;
        float a1 = v * w1;
        #pragma unroll
        for (int off = 32; off > 0; off >>= 1) {
            a0 += __shfl_down(a0, off);
            a1 += __shfl_down(a1, off);
        }
        if (lane == 0) {
            out[(size_t)r * 2 + 0] = a0 + b0;
            out[(size_t)r * 2 + 1] = a1 + b1;
        }
    }
}

extern "C" void kernel_launch(void* const* d_in, const int* in_sizes, int n_in,
                              void* d_out, int out_size, void* d_ws, size_t ws_size,
                              hipStream_t stream) {
    const float* x    = (const float*)d_in[0];
    const int*   ei   = (const int*)d_in[1];
    const float* Wl   = (const float*)d_in[2];
    const float* bl   = (const float*)d_in[3];
    const float* Wr   = (const float*)d_in[4];
    const float* Wout = (const float*)d_in[5];
    const float* bout = (const float*)d_in[6];
    float*       out  = (float*)d_out;

    const int N = in_sizes[0] / D;
    const int E = in_sizes[1] / 2;
    const int* src = ei;
    const int* dst = ei + E;

    char* ws = (char*)d_ws;
    float* deg = (float*)ws;
    size_t off = (((size_t)N * 4) + 255) & ~(size_t)255;
    float* bufA = (float*)(ws + off);
    float* bufB = (float*)(ws + off + (size_t)N * D * 4);

    const size_t hBytes = (size_t)N * D * 4;
    hipMemsetAsync(deg, 0, (size_t)N * 4, stream);
    hipMemsetAsync(bufA, 0, hBytes, stream);

    deg_kernel<<<1024, 256, 0, stream>>>(dst, deg, E);

    const int gridT = (N + 63) / 64;

    // Layer 0: h = x
    aggregate_kernel<<<4096, 256, 0, stream>>>(x, src, dst, bufA, E);
    transform_kernel<<<gridT, 256, 0, stream>>>(bufA, x, Wl, bl, Wr, deg, bufA, N, 1);

    // Layer 1: h = bufA
    hipMemsetAsync(bufB, 0, hBytes, stream);
    aggregate_kernel<<<4096, 256, 0, stream>>>(bufA, src, dst, bufB, E);
    transform_kernel<<<gridT, 256, 0, stream>>>(bufB, bufA, Wl + D * D, bl + D, Wr + D * D, deg, bufB, N, 1);

    // Layer 2: h = bufB
    hipMemsetAsync(bufA, 0, hBytes, stream);
    aggregate_kernel<<<4096, 256, 0, stream>>>(bufB, src, dst, bufA, E);
    transform_kernel<<<gridT, 256, 0, stream>>>(bufA, bufB, Wl + 2 * D * D, bl + 2 * D, Wr + 2 * D * D, deg, bufA, N, 0);

    classify_kernel<<<4096, 256, 0, stream>>>(bufA, Wout, bout, out, N);
}

// Round 2
// 618.873 us; speedup vs baseline: 1.8571x; 1.8571x over previous
//
#include <hip/hip_runtime.h>

#define D 64

// ================= CSR build =================

__global__ void hist_kernel(const int* __restrict__ dst, int* __restrict__ deg, int E) {
    int i = blockIdx.x * blockDim.x + threadIdx.x;
    int n = gridDim.x * blockDim.x;
    for (int e = i; e < E; e += n) atomicAdd(&deg[dst[e]], 1);
}

__global__ void invdeg_kernel(const int* __restrict__ deg, float* __restrict__ inv, int N) {
    int i = blockIdx.x * blockDim.x + threadIdx.x;
    if (i < N) inv[i] = 1.0f / fmaxf((float)deg[i], 1.0f);
}

__global__ void blocksum_kernel(const int* __restrict__ deg, int* __restrict__ blockSums, int N) {
    __shared__ int s[256];
    int t = threadIdx.x;
    int i = blockIdx.x * 256 + t;
    s[t] = (i < N) ? deg[i] : 0;
    __syncthreads();
    for (int d = 128; d > 0; d >>= 1) {
        if (t < d) s[t] += s[t + d];
        __syncthreads();
    }
    if (t == 0) blockSums[blockIdx.x] = s[0];
}

// single block, 512 threads; nb <= 512
__global__ void scanpartials_kernel(const int* __restrict__ blockSums, int* __restrict__ blockOffs, int nb) {
    __shared__ int s[512];
    int t = threadIdx.x;
    int v = (t < nb) ? blockSums[t] : 0;
    s[t] = v;
    __syncthreads();
    for (int d = 1; d < 512; d <<= 1) {
        int add = (t >= d) ? s[t - d] : 0;
        __syncthreads();
        s[t] += add;
        __syncthreads();
    }
    if (t < nb) blockOffs[t] = s[t] - v;  // exclusive
}

__global__ void scanblock_kernel(const int* __restrict__ deg, const int* __restrict__ blockOffs,
                                 int* __restrict__ rowStart, int N) {
    __shared__ int s[256];
    int t = threadIdx.x;
    int i = blockIdx.x * 256 + t;
    int v = (i < N) ? deg[i] : 0;
    s[t] = v;
    __syncthreads();
    for (int d = 1; d < 256; d <<= 1) {
        int add = (t >= d) ? s[t - d] : 0;
        __syncthreads();
        s[t] += add;
        __syncthreads();
    }
    if (i < N) rowStart[i] = blockOffs[blockIdx.x] + s[t] - v;
    if (i == N - 1) rowStart[N] = blockOffs[blockIdx.x] + s[t];
}

__global__ void scatter_kernel(const int* __restrict__ src, const int* __restrict__ dst,
                               const int* __restrict__ rowStart, int* __restrict__ cursor,
                               int* __restrict__ csr, int E) {
    int i = blockIdx.x * blockDim.x + threadIdx.x;
    int n = gridDim.x * blockDim.x;
    for (int e = i; e < E; e += n) {
        int d = dst[e];
        int pos = rowStart[d] + atomicAdd(&cursor[d], 1);
        csr[pos] = src[e];
    }
}

// ================= aggregate: agg[n][:] = inv_deg[n] * sum_{j in N(n)} h[j][:] =================
__global__ void aggregate_csr(const float* __restrict__ h, const int* __restrict__ rowStart,
                              const int* __restrict__ csr, const float* __restrict__ inv_deg,
                              float* __restrict__ agg, int N) {
    int wid  = (blockIdx.x * blockDim.x + threadIdx.x) >> 6;
    int lane = threadIdx.x & 63;
    int nw   = (gridDim.x * blockDim.x) >> 6;
    for (int node = wid; node < N; node += nw) {
        int beg = rowStart[node], end = rowStart[node + 1];
        float acc = 0.0f;
        for (int p = beg; p < end; ++p) {
            int s = csr[p];                       // wave-uniform (broadcast) load
            acc += h[(size_t)s * D + lane];       // coalesced 256B gather
        }
        agg[(size_t)node * D + lane] = acc * inv_deg[node];
    }
}

// ================= transform: out = [relu](agg @ Wl^T + bl + h @ Wr^T) [+ classifier] =================
// Weights live in registers (lane o holds row o of Wl and Wr). agg/h rows staged
// in wave-private LDS, read back as broadcast ds_read_b128. No __syncthreads needed.
// Safe for out == agg (row fully consumed before overwrite; one wave owns a row).
template <bool RELU, bool CLS>
__global__ __launch_bounds__(256) void transform_reg(
    const float* __restrict__ agg, const float* __restrict__ h,
    const float* __restrict__ Wl, const float* __restrict__ bl,
    const float* __restrict__ Wr,
    const float* __restrict__ Wout, const float* __restrict__ bout,
    float* __restrict__ out, int N) {
    int t = threadIdx.x;
    int lane = t & 63;
    int w = t >> 6;  // wave id 0..3

    float4 wl[16], wr[16];
    const float4* Wl4 = (const float4*)(Wl + lane * D);
    const float4* Wr4 = (const float4*)(Wr + lane * D);
#pragma unroll
    for (int c = 0; c < 16; ++c) { wl[c] = Wl4[c]; wr[c] = Wr4[c]; }
    float b = bl[lane];
    float w0 = 0.f, w1 = 0.f, b0 = 0.f, b1 = 0.f;
    if (CLS) { w0 = Wout[lane]; w1 = Wout[D + lane]; b0 = bout[0]; b1 = bout[1]; }

    __shared__ float rows[4][2][D];  // [wave][agg/h][feature] — wave-private

    int stride = gridDim.x * 4;
    for (int r = blockIdx.x * 4 + w; r < N; r += stride) {
        rows[w][0][lane] = agg[(size_t)r * D + lane];  // coalesced row loads
        rows[w][1][lane] = h[(size_t)r * D + lane];
        float accL = 0.0f, accR = 0.0f;
#pragma unroll
        for (int c = 0; c < 16; ++c) {
            float4 a4 = *(const float4*)&rows[w][0][c * 4];  // broadcast b128
            float4 h4 = *(const float4*)&rows[w][1][c * 4];
            accL += a4.x * wl[c].x + a4.y * wl[c].y + a4.z * wl[c].z + a4.w * wl[c].w;
            accR += h4.x * wr[c].x + h4.y * wr[c].y + h4.z * wr[c].z + h4.w * wr[c].w;
        }
        float v = accL + b + accR;  // inv_deg already folded into agg
        if (RELU) v = fmaxf(v, 0.0f);
        if (CLS) {
            float a0 = v * w0;
            float a1 = v * w1;
#pragma unroll
            for (int off = 32; off > 0; off >>= 1) {
                a0 += __shfl_down(a0, off);
                a1 += __shfl_down(a1, off);
            }
            if (lane == 0) {
                out[(size_t)r * 2 + 0] = a0 + b0;
                out[(size_t)r * 2 + 1] = a1 + b1;
            }
        } else {
            out[(size_t)r * D + lane] = v;
        }
    }
}

extern "C" void kernel_launch(void* const* d_in, const int* in_sizes, int n_in,
                              void* d_out, int out_size, void* d_ws, size_t ws_size,
                              hipStream_t stream) {
    const float* x    = (const float*)d_in[0];
    const int*   ei   = (const int*)d_in[1];
    const float* Wl   = (const float*)d_in[2];
    const float* bl   = (const float*)d_in[3];
    const float* Wr   = (const float*)d_in[4];
    const float* Wout = (const float*)d_in[5];
    const float* bout = (const float*)d_in[6];
    float*       out  = (float*)d_out;

    const int N = in_sizes[0] / D;
    const int E = in_sizes[1] / 2;
    const int* src = ei;
    const int* dst = ei + E;
    const int nb = (N + 255) / 256;

    // workspace carve-up (256B aligned)
    char* ws = (char*)d_ws;
    size_t off = 0;
    auto alloc = [&](size_t bytes) {
        char* p = ws + off;
        off = (off + bytes + 255) & ~(size_t)255;
        return p;
    };
    int*   deg_i     = (int*)alloc((size_t)N * 4);
    float* inv_deg   = (float*)alloc((size_t)N * 4);
    int*   rowStart  = (int*)alloc((size_t)(N + 1) * 4);
    int*   cursor    = (int*)alloc((size_t)N * 4);
    int*   blockSums = (int*)alloc((size_t)nb * 4);
    int*   blockOffs = (int*)alloc((size_t)nb * 4);
    int*   csr       = (int*)alloc((size_t)E * 4);
    float* bufA      = (float*)alloc((size_t)N * D * 4);
    float* bufB      = (float*)alloc((size_t)N * D * 4);

    hipMemsetAsync(deg_i, 0, (size_t)N * 4, stream);
    hipMemsetAsync(cursor, 0, (size_t)N * 4, stream);

    // ---- CSR build (once, reused by all 3 layers) ----
    hist_kernel<<<1024, 256, 0, stream>>>(dst, deg_i, E);
    invdeg_kernel<<<nb, 256, 0, stream>>>(deg_i, inv_deg, N);
    blocksum_kernel<<<nb, 256, 0, stream>>>(deg_i, blockSums, N);
    scanpartials_kernel<<<1, 512, 0, stream>>>(blockSums, blockOffs, nb);
    scanblock_kernel<<<nb, 256, 0, stream>>>(deg_i, blockOffs, rowStart, N);
    scatter_kernel<<<2048, 256, 0, stream>>>(src, dst, rowStart, cursor, csr, E);

    // ---- 3 layers ----
    aggregate_csr<<<2048, 256, 0, stream>>>(x, rowStart, csr, inv_deg, bufA, N);
    transform_reg<true, false><<<2048, 256, 0, stream>>>(bufA, x, Wl, bl, Wr, nullptr, nullptr, bufA, N);

    aggregate_csr<<<2048, 256, 0, stream>>>(bufA, rowStart, csr, inv_deg, bufB, N);
    transform_reg<true, false><<<2048, 256, 0, stream>>>(bufB, bufA, Wl + D * D, bl + D, Wr + D * D, nullptr, nullptr, bufB, N);

    aggregate_csr<<<2048, 256, 0, stream>>>(bufB, rowStart, csr, inv_deg, bufA, N);
    transform_reg<false, true><<<2048, 256, 0, stream>>>(bufA, bufB, Wl + 2 * D * D, bl + 2 * D, Wr + 2 * D * D, Wout, bout, out, N);
}